// Round 1
// baseline (604.671 us; speedup 1.0000x reference)
//
#include <hip/hip_runtime.h>

// AttentionBlock: GN -> 1x1x1 conv (QKV) -> per-(voxel,head) attention with
// T5 rel-pos bias + q/k LayerNorm -> out-proj -> x + gamma*o.
// Shapes: T=64,B=1,C=768,H=W=D=8 (VOX=512), He=12, hd=64, groups=12.
// All matmul-shaped compute in bf16 MFMA (gamma~1e-6 makes o-path error
// irrelevant: threshold 0.108 vs predicted ~1e-6).
//
// d_ws layout (bytes, all 256-aligned), total ~196.5 MB:
//   stats  @0        : 768*2 f32   (mu, rstd per (tb,group))
//   bias_d @6144     : 12*128 f32  (rel-pos bias per head, indexed by t-s+63)
//   winb   @12288    : 2304*768 bf16
//   woutb  @3551232  : 768*768 bf16
//   xnT    @4730880  : 32768*768 bf16  (normalized x, [n=(t*512+vox)][c]; reused as oT)
//   qkvT   @55062528 : 32768*2304 bf16 ([n][he*192 + {q:0-63,k:64-127,v:128-191}])

typedef unsigned int u32;
typedef unsigned short u16;
typedef __attribute__((ext_vector_type(4))) float f32x4;
typedef __attribute__((ext_vector_type(8))) short s16x8;

__device__ __forceinline__ float bfl(u32 w){ union{u32 i; float f;} u; u.i = w<<16; return u.f; }
__device__ __forceinline__ float bfh(u32 w){ union{u32 i; float f;} u; u.i = w & 0xffff0000u; return u.f; }
__device__ __forceinline__ u16 f2bf(float f){ union{float ff; u32 i;} u; u.ff = f; u32 r = u.i + 0x7fffu + ((u.i>>16)&1u); return (u16)(r>>16); }
__device__ __forceinline__ u32 pk2(float a, float b){ return (u32)f2bf(a) | ((u32)f2bf(b)<<16); }

// ---------------- K0a: rel-pos bias table (bucket depends only on t-s) -----
__global__ void k_bias(const float* __restrict__ rel, float* __restrict__ bias_d){
  int d = threadIdx.x;
  if (d < 127){
    int delta = d - 63;                    // t - s
    int ret = (delta < 0) ? 16 : 0;
    int a = delta < 0 ? -delta : delta;
    int bkt;
    if (a < 8) bkt = a;
    else {
      float lr = (logf((float)a * 0.125f) / logf(16.0f)) * 8.0f;
      int vl = 8 + (int)lr;
      bkt = vl > 15 ? 15 : vl;
    }
    bkt += ret;
    for (int he = 0; he < 12; ++he) bias_d[he*128 + d] = rel[bkt*12 + he];
  }
}

// ---------------- K0b: cast weights to bf16 --------------------------------
__global__ void k_cast(const float* __restrict__ a, const float* __restrict__ b,
                       u16* __restrict__ ab, u16* __restrict__ bb){
  const int n1 = 2304*768, n2 = 768*768;
  for (int i = blockIdx.x*blockDim.x + threadIdx.x; i < n1+n2; i += gridDim.x*blockDim.x){
    if (i < n1) ab[i] = f2bf(a[i]);
    else        bb[i-n1] = f2bf(b[i-n1]);
  }
}

// ---------------- K1: GroupNorm stats (one block per (tb,g)) ---------------
__global__ __launch_bounds__(256) void k_stats(const float* __restrict__ x, float* __restrict__ stats){
  __shared__ float red[8];
  const float4* xb = (const float4*)(x + (size_t)blockIdx.x * 32768);
  float s = 0.f, s2 = 0.f;
  for (int i = threadIdx.x; i < 8192; i += 256){
    float4 v = xb[i];
    s  += v.x + v.y + v.z + v.w;
    s2 += v.x*v.x + v.y*v.y + v.z*v.z + v.w*v.w;
  }
  #pragma unroll
  for (int off = 32; off; off >>= 1){ s += __shfl_down(s, off); s2 += __shfl_down(s2, off); }
  int wid = threadIdx.x >> 6;
  if ((threadIdx.x & 63) == 0){ red[wid*2] = s; red[wid*2+1] = s2; }
  __syncthreads();
  if (threadIdx.x == 0){
    float ts = 0.f, ts2 = 0.f;
    for (int w = 0; w < 4; ++w){ ts += red[w*2]; ts2 += red[w*2+1]; }
    float mu  = ts * (1.f/32768.f);
    float var = ts2 * (1.f/32768.f) - mu*mu;
    stats[blockIdx.x*2]   = mu;
    stats[blockIdx.x*2+1] = rsqrtf(var + 1e-5f);
  }
}

// ---------------- K2: normalize + transpose -> xnT[n][c] bf16 --------------
__global__ __launch_bounds__(256) void k_norm(const float* __restrict__ x, const float* __restrict__ stats,
                                              const float* __restrict__ w1, u16* __restrict__ xnT){
  __shared__ float ld[64][65];
  const int b = blockIdx.x;
  const int tb = b / 96, rem = b % 96, cb = rem >> 3, vb = rem & 7;
  const float mu  = stats[(tb*12+cb)*2];
  const float inv = stats[(tb*12+cb)*2+1];
  const int tid = threadIdx.x;
  #pragma unroll
  for (int it = 0; it < 4; ++it){
    int chunk = it*256 + tid;
    int cl = chunk >> 4, v4 = chunk & 15;
    float w = w1[cb*64 + cl] * inv;
    float4 v = *(const float4*)(x + ((size_t)(tb*768 + cb*64 + cl)*512 + vb*64 + v4*4));
    ld[cl][v4*4+0] = (v.x - mu) * w;
    ld[cl][v4*4+1] = (v.y - mu) * w;
    ld[cl][v4*4+2] = (v.z - mu) * w;
    ld[cl][v4*4+3] = (v.w - mu) * w;
  }
  __syncthreads();
  #pragma unroll
  for (int it = 0; it < 2; ++it){
    int chunk = it*256 + tid;
    int vl = chunk >> 3, p = chunk & 7;
    u32 ow[4];
    #pragma unroll
    for (int j = 0; j < 4; ++j)
      ow[j] = pk2(ld[p*8 + j*2][vl], ld[p*8 + j*2 + 1][vl]);
    uint4 q4; q4.x = ow[0]; q4.y = ow[1]; q4.z = ow[2]; q4.w = ow[3];
    *(uint4*)(xnT + ((size_t)(tb*512 + vb*64 + vl)*768 + cb*64 + p*8)) = q4;
  }
}

// ---------------- K3/K5: bf16 MFMA GEMM, 128x128 tile, D[n][m] -------------
// D[n][m] = sum_k Bt[n][k]*At[m][k]  (+ epilogue). At: MxK, Bt: NxK, row-major.
// epi==1: outT[n*M+m] = bf16(acc + bias[m])
// epi==2: t=n>>9, vox=n&511; out[(t*768+m)*512+vox] = x[...] + gamma[m]*(acc + bout[m])
__global__ __launch_bounds__(256) void k_gemm(const u16* __restrict__ At, const u16* __restrict__ Bt,
    const int M, const int K, const int mtiles, const int epi,
    const float* __restrict__ bias, u16* __restrict__ outT,
    const float* __restrict__ xres, const float* __restrict__ gamma,
    const float* __restrict__ bout, float* __restrict__ outp)
{
  __shared__ u16 lta[128*32];
  __shared__ u16 ltb[128*32];
  const int tid = threadIdx.x;
  const int l = tid & 63;
  const int wid = tid >> 6;
  const int wm = wid & 1, wn = wid >> 1;
  const int mt = blockIdx.x % mtiles, nt = blockIdx.x / mtiles;
  const f32x4 z = {0.f, 0.f, 0.f, 0.f};
  f32x4 acc[4][4];
  #pragma unroll
  for (int i = 0; i < 4; ++i)
    #pragma unroll
    for (int j = 0; j < 4; ++j) acc[i][j] = z;
  const int nk = K >> 5;
  const int r0 = tid >> 2, q0 = tid & 3;
  for (int kt = 0; kt < nk; ++kt){
    uint4 av0 = *(const uint4*)(At + (size_t)(mt*128 + r0     )*K + kt*32 + q0*8);
    uint4 bv0 = *(const uint4*)(Bt + (size_t)(nt*128 + r0     )*K + kt*32 + q0*8);
    uint4 av1 = *(const uint4*)(At + (size_t)(mt*128 + r0 + 64)*K + kt*32 + q0*8);
    uint4 bv1 = *(const uint4*)(Bt + (size_t)(nt*128 + r0 + 64)*K + kt*32 + q0*8);
    __syncthreads();
    *(uint4*)&lta[(r0     )*32 + q0*8] = av0;
    *(uint4*)&ltb[(r0     )*32 + q0*8] = bv0;
    *(uint4*)&lta[(r0 + 64)*32 + q0*8] = av1;
    *(uint4*)&ltb[(r0 + 64)*32 + q0*8] = bv1;
    __syncthreads();
    s16x8 fa[4], fb[4];
    #pragma unroll
    for (int f = 0; f < 4; ++f){
      fa[f] = *(const s16x8*)&ltb[(wn*64 + f*16 + (l&15))*32 + ((l>>4)<<3)];
      fb[f] = *(const s16x8*)&lta[(wm*64 + f*16 + (l&15))*32 + ((l>>4)<<3)];
    }
    #pragma unroll
    for (int fn = 0; fn < 4; ++fn)
      #pragma unroll
      for (int fm = 0; fm < 4; ++fm)
        acc[fn][fm] = __builtin_amdgcn_mfma_f32_16x16x32_bf16(fa[fn], fb[fm], acc[fn][fm], 0, 0, 0);
  }
  const int rsub = (l>>4) << 2, cbase = l & 15;
  if (epi == 1){
    #pragma unroll
    for (int fn = 0; fn < 4; ++fn)
      #pragma unroll
      for (int fm = 0; fm < 4; ++fm){
        const int n0 = nt*128 + wn*64 + fn*16 + rsub;
        const int m  = mt*128 + wm*64 + fm*16 + cbase;
        const float bm = bias[m];
        #pragma unroll
        for (int r = 0; r < 4; ++r)
          outT[(size_t)(n0 + r)*M + m] = f2bf(acc[fn][fm][r] + bm);
      }
  } else {
    #pragma unroll
    for (int fn = 0; fn < 4; ++fn)
      #pragma unroll
      for (int fm = 0; fm < 4; ++fm){
        const int n0 = nt*128 + wn*64 + fn*16 + rsub;
        const int m  = mt*128 + wm*64 + fm*16 + cbase;
        const int t = n0 >> 9, vox = n0 & 511;
        const size_t idx = ((size_t)t*768 + m)*512 + vox;
        const float gm = gamma[m], bo = bout[m];
        const float4 xv = *(const float4*)(xres + idx);
        float4 ov;
        ov.x = xv.x + gm*(acc[fn][fm][0] + bo);
        ov.y = xv.y + gm*(acc[fn][fm][1] + bo);
        ov.z = xv.z + gm*(acc[fn][fm][2] + bo);
        ov.w = xv.w + gm*(acc[fn][fm][3] + bo);
        *(float4*)(outp + idx) = ov;
      }
  }
}

// ---------------- K4: attention, 1 wave per (vox, head) --------------------
__device__ __forceinline__ void ln_row(const uint4* g, const float* __restrict__ w,
                                       const float* __restrict__ b, u16* dst){
  uint4 raw[8];
  #pragma unroll
  for (int i = 0; i < 8; ++i) raw[i] = g[i];
  float s = 0.f, s2 = 0.f;
  #pragma unroll
  for (int i = 0; i < 8; ++i){
    const u32* p = (const u32*)&raw[i];
    #pragma unroll
    for (int j = 0; j < 4; ++j){
      float v0 = bfl(p[j]), v1 = bfh(p[j]);
      s += v0 + v1; s2 += v0*v0 + v1*v1;
    }
  }
  float mu  = s * (1.f/64.f);
  float inv = rsqrtf(s2*(1.f/64.f) - mu*mu + 1e-5f);
  #pragma unroll
  for (int i = 0; i < 8; ++i){
    const u32* p = (const u32*)&raw[i];
    u32 ow[4];
    #pragma unroll
    for (int j = 0; j < 4; ++j){
      int c = i*8 + j*2;
      float v0 = (bfl(p[j]) - mu)*inv*w[c]   + b[c];
      float v1 = (bfh(p[j]) - mu)*inv*w[c+1] + b[c+1];
      ow[j] = pk2(v0, v1);
    }
    uint4 q4; q4.x = ow[0]; q4.y = ow[1]; q4.z = ow[2]; q4.w = ow[3];
    *(uint4*)(dst + i*8) = q4;
  }
}

__global__ __launch_bounds__(64) void k_attn(const u16* __restrict__ qkvT, const float* __restrict__ bias_d,
    const float* __restrict__ qn_w, const float* __restrict__ qn_b,
    const float* __restrict__ kn_w, const float* __restrict__ kn_b,
    u16* __restrict__ oT)
{
  __shared__ u16 qt[64][72], ktl[64][72], vtl[64][72], pt[64][72];
  __shared__ float bd[128];
  const int l = threadIdx.x;
  const int he = blockIdx.x % 12;
  const int vox = blockIdx.x / 12;
  for (int i = l; i < 127; i += 64) bd[i] = bias_d[he*128 + i];
  const size_t rb = ((size_t)(l*512 + vox))*2304 + (size_t)he*192;
  const uint4* g = (const uint4*)(qkvT + rb);
  ln_row(g,     qn_w, qn_b, &qt[l][0]);
  ln_row(g + 8, kn_w, kn_b, &ktl[l][0]);
  #pragma unroll
  for (int i = 0; i < 8; ++i){
    uint4 r = g[16 + i];
    const u32* p = (const u32*)&r;
    #pragma unroll
    for (int j = 0; j < 4; ++j){
      int c = i*8 + j*2;
      vtl[c][l]   = (u16)(p[j] & 0xffffu);
      vtl[c+1][l] = (u16)(p[j] >> 16);
    }
  }
  __syncthreads();
  const f32x4 z = {0.f, 0.f, 0.f, 0.f};
  f32x4 sa[4][4];
  #pragma unroll
  for (int i = 0; i < 4; ++i)
    #pragma unroll
    for (int j = 0; j < 4; ++j) sa[i][j] = z;
  #pragma unroll
  for (int ks = 0; ks < 2; ++ks){
    s16x8 fq[4], fk[4];
    #pragma unroll
    for (int f = 0; f < 4; ++f){
      fq[f] = *(const s16x8*)&qt [f*16 + (l&15)][ks*32 + ((l>>4)<<3)];
      fk[f] = *(const s16x8*)&ktl[f*16 + (l&15)][ks*32 + ((l>>4)<<3)];
    }
    #pragma unroll
    for (int fr = 0; fr < 4; ++fr)
      #pragma unroll
      for (int fc = 0; fc < 4; ++fc)
        sa[fr][fc] = __builtin_amdgcn_mfma_f32_16x16x32_bf16(fq[fr], fk[fc], sa[fr][fc], 0, 0, 0);
  }
  const int cbase = l & 15;
  const int rsub = (l >> 4) << 2;
  #pragma unroll
  for (int fr = 0; fr < 4; ++fr){
    #pragma unroll
    for (int r = 0; r < 4; ++r){
      const int row = fr*16 + rsub + r;
      float v0 = sa[fr][0][r]*0.125f + bd[row - cbase      + 63];
      float v1 = sa[fr][1][r]*0.125f + bd[row - cbase - 16 + 63];
      float v2 = sa[fr][2][r]*0.125f + bd[row - cbase - 32 + 63];
      float v3 = sa[fr][3][r]*0.125f + bd[row - cbase - 48 + 63];
      float m = fmaxf(fmaxf(v0, v1), fmaxf(v2, v3));
      #pragma unroll
      for (int off = 1; off < 16; off <<= 1) m = fmaxf(m, __shfl_xor(m, off));
      v0 = __expf(v0 - m); v1 = __expf(v1 - m); v2 = __expf(v2 - m); v3 = __expf(v3 - m);
      float sum = v0 + v1 + v2 + v3;
      #pragma unroll
      for (int off = 1; off < 16; off <<= 1) sum += __shfl_xor(sum, off);
      float rs = 1.0f / sum;
      pt[row][cbase]      = f2bf(v0*rs);
      pt[row][cbase + 16] = f2bf(v1*rs);
      pt[row][cbase + 32] = f2bf(v2*rs);
      pt[row][cbase + 48] = f2bf(v3*rs);
    }
  }
  __syncthreads();
  f32x4 oa[4][4];
  #pragma unroll
  for (int i = 0; i < 4; ++i)
    #pragma unroll
    for (int j = 0; j < 4; ++j) oa[i][j] = z;
  #pragma unroll
  for (int ks = 0; ks < 2; ++ks){
    s16x8 fp[4], fv[4];
    #pragma unroll
    for (int f = 0; f < 4; ++f){
      fp[f] = *(const s16x8*)&pt [f*16 + (l&15)][ks*32 + ((l>>4)<<3)];
      fv[f] = *(const s16x8*)&vtl[f*16 + (l&15)][ks*32 + ((l>>4)<<3)];
    }
    #pragma unroll
    for (int ft = 0; ft < 4; ++ft)
      #pragma unroll
      for (int fc = 0; fc < 4; ++fc)
        oa[ft][fc] = __builtin_amdgcn_mfma_f32_16x16x32_bf16(fp[ft], fv[fc], oa[ft][fc], 0, 0, 0);
  }
  #pragma unroll
  for (int ft = 0; ft < 4; ++ft)
    #pragma unroll
    for (int fc = 0; fc < 4; ++fc){
      const int t0 = ft*16 + rsub;
      const int c  = fc*16 + cbase;
      #pragma unroll
      for (int r = 0; r < 4; ++r)
        oT[((size_t)((t0 + r)*512 + vox))*768 + he*64 + c] = f2bf(oa[ft][fc][r]);
    }
}

// ---------------- launch ---------------------------------------------------
extern "C" void kernel_launch(void* const* d_in, const int* in_sizes, int n_in,
                              void* d_out, int out_size, void* d_ws, size_t ws_size,
                              hipStream_t stream) {
  (void)in_sizes; (void)n_in; (void)out_size; (void)ws_size;
  const float* x      = (const float*)d_in[0];
  const float* norm1w = (const float*)d_in[1];
  const float* w_in   = (const float*)d_in[2];
  const float* b_in   = (const float*)d_in[3];
  const float* qn_w   = (const float*)d_in[4];
  const float* qn_b   = (const float*)d_in[5];
  const float* kn_w   = (const float*)d_in[6];
  const float* kn_b   = (const float*)d_in[7];
  const float* rel    = (const float*)d_in[8];
  const float* w_out  = (const float*)d_in[9];
  const float* b_out  = (const float*)d_in[10];
  const float* gamma  = (const float*)d_in[11];
  float* out = (float*)d_out;

  char* ws = (char*)d_ws;
  float* stats  = (float*)(ws + 0);
  float* bias_d = (float*)(ws + 6144);
  u16*   winb   = (u16*)(ws + 12288);
  u16*   woutb  = (u16*)(ws + 3551232);
  u16*   xnT    = (u16*)(ws + 4730880);
  u16*   oT     = xnT;  // xnT dead after GEMM1; reuse for attention output
  u16*   qkvT   = (u16*)(ws + 55062528);

  k_bias <<<1,    128, 0, stream>>>(rel, bias_d);
  k_cast <<<2048, 256, 0, stream>>>(w_in, w_out, winb, woutb);
  k_stats<<<768,  256, 0, stream>>>(x, stats);
  k_norm <<<6144, 256, 0, stream>>>(x, stats, norm1w, xnT);
  k_gemm <<<4608, 256, 0, stream>>>(winb, xnT, 2304, 768, 18, 1,
                                    b_in, qkvT, nullptr, nullptr, nullptr, nullptr);
  k_attn <<<6144, 64,  0, stream>>>(qkvT, bias_d, qn_w, qn_b, kn_w, kn_b, oT);
  k_gemm <<<1536, 256, 0, stream>>>(woutb, oT, 768, 768, 6, 2,
                                    nullptr, nullptr, x, gamma, b_out, out);
}

// Round 2
// 574.003 us; speedup vs baseline: 1.0534x; 1.0534x over previous
//
#include <hip/hip_runtime.h>

// AttentionBlock: GN -> 1x1x1 conv (QKV) -> per-(voxel,head) attention with
// T5 rel-pos bias + q/k LayerNorm -> out-proj -> x + gamma*o.
// Shapes: T=64,B=1,C=768,H=W=D=8 (VOX=512), He=12, hd=64, groups=12.
//
// R2: (a) k_gemm stages via global_load_lds width=16 (m97 pattern; LDS layout
//     already linear in tid*16B). (b) k_attn: 4 waves/block (one t-strip each),
//     coalesced (row,chunk) loads, in-register LN via 8-lane shfl reduce,
//     P reuses Q's LDS strip -> 28.2KB/block -> 20 waves/CU.

typedef unsigned int u32;
typedef unsigned short u16;
typedef __attribute__((ext_vector_type(4))) float f32x4;
typedef __attribute__((ext_vector_type(8))) short s16x8;

__device__ __forceinline__ float bfl(u32 w){ union{u32 i; float f;} u; u.i = w<<16; return u.f; }
__device__ __forceinline__ float bfh(u32 w){ union{u32 i; float f;} u; u.i = w & 0xffff0000u; return u.f; }
__device__ __forceinline__ u16 f2bf(float f){ union{float ff; u32 i;} u; u.ff = f; u32 r = u.i + 0x7fffu + ((u.i>>16)&1u); return (u16)(r>>16); }
__device__ __forceinline__ u32 pk2(float a, float b){ return (u32)f2bf(a) | ((u32)f2bf(b)<<16); }

__device__ __forceinline__ void gll16(const u16* g, u16* l){
  __builtin_amdgcn_global_load_lds((const __attribute__((address_space(1))) void*)g,
                                   (__attribute__((address_space(3))) void*)l, 16, 0, 0);
}

// ---------------- K0a: rel-pos bias table (bucket depends only on t-s) -----
__global__ void k_bias(const float* __restrict__ rel, float* __restrict__ bias_d){
  int d = threadIdx.x;
  if (d < 127){
    int delta = d - 63;                    // t - s
    int ret = (delta < 0) ? 16 : 0;
    int a = delta < 0 ? -delta : delta;
    int bkt;
    if (a < 8) bkt = a;
    else {
      float lr = (logf((float)a * 0.125f) / logf(16.0f)) * 8.0f;
      int vl = 8 + (int)lr;
      bkt = vl > 15 ? 15 : vl;
    }
    bkt += ret;
    for (int he = 0; he < 12; ++he) bias_d[he*128 + d] = rel[bkt*12 + he];
  }
}

// ---------------- K0b: cast weights to bf16 --------------------------------
__global__ void k_cast(const float* __restrict__ a, const float* __restrict__ b,
                       u16* __restrict__ ab, u16* __restrict__ bb){
  const int n1 = 2304*768, n2 = 768*768;
  for (int i = blockIdx.x*blockDim.x + threadIdx.x; i < n1+n2; i += gridDim.x*blockDim.x){
    if (i < n1) ab[i] = f2bf(a[i]);
    else        bb[i-n1] = f2bf(b[i-n1]);
  }
}

// ---------------- K1: GroupNorm stats (one block per (tb,g)) ---------------
__global__ __launch_bounds__(256) void k_stats(const float* __restrict__ x, float* __restrict__ stats){
  __shared__ float red[8];
  const float4* xb = (const float4*)(x + (size_t)blockIdx.x * 32768);
  float s = 0.f, s2 = 0.f;
  for (int i = threadIdx.x; i < 8192; i += 256){
    float4 v = xb[i];
    s  += v.x + v.y + v.z + v.w;
    s2 += v.x*v.x + v.y*v.y + v.z*v.z + v.w*v.w;
  }
  #pragma unroll
  for (int off = 32; off; off >>= 1){ s += __shfl_down(s, off); s2 += __shfl_down(s2, off); }
  int wid = threadIdx.x >> 6;
  if ((threadIdx.x & 63) == 0){ red[wid*2] = s; red[wid*2+1] = s2; }
  __syncthreads();
  if (threadIdx.x == 0){
    float ts = 0.f, ts2 = 0.f;
    for (int w = 0; w < 4; ++w){ ts += red[w*2]; ts2 += red[w*2+1]; }
    float mu  = ts * (1.f/32768.f);
    float var = ts2 * (1.f/32768.f) - mu*mu;
    stats[blockIdx.x*2]   = mu;
    stats[blockIdx.x*2+1] = rsqrtf(var + 1e-5f);
  }
}

// ---------------- K2: normalize + transpose -> xnT[n][c] bf16 --------------
__global__ __launch_bounds__(256) void k_norm(const float* __restrict__ x, const float* __restrict__ stats,
                                              const float* __restrict__ w1, u16* __restrict__ xnT){
  __shared__ float ld[64][65];
  const int b = blockIdx.x;
  const int tb = b / 96, rem = b % 96, cb = rem >> 3, vb = rem & 7;
  const float mu  = stats[(tb*12+cb)*2];
  const float inv = stats[(tb*12+cb)*2+1];
  const int tid = threadIdx.x;
  #pragma unroll
  for (int it = 0; it < 4; ++it){
    int chunk = it*256 + tid;
    int cl = chunk >> 4, v4 = chunk & 15;
    float w = w1[cb*64 + cl] * inv;
    float4 v = *(const float4*)(x + ((size_t)(tb*768 + cb*64 + cl)*512 + vb*64 + v4*4));
    ld[cl][v4*4+0] = (v.x - mu) * w;
    ld[cl][v4*4+1] = (v.y - mu) * w;
    ld[cl][v4*4+2] = (v.z - mu) * w;
    ld[cl][v4*4+3] = (v.w - mu) * w;
  }
  __syncthreads();
  #pragma unroll
  for (int it = 0; it < 2; ++it){
    int chunk = it*256 + tid;
    int vl = chunk >> 3, p = chunk & 7;
    u32 ow[4];
    #pragma unroll
    for (int j = 0; j < 4; ++j)
      ow[j] = pk2(ld[p*8 + j*2][vl], ld[p*8 + j*2 + 1][vl]);
    uint4 q4; q4.x = ow[0]; q4.y = ow[1]; q4.z = ow[2]; q4.w = ow[3];
    *(uint4*)(xnT + ((size_t)(tb*512 + vb*64 + vl)*768 + cb*64 + p*8)) = q4;
  }
}

// ---------------- K3/K5: bf16 MFMA GEMM, 128x128 tile, D[n][m] -------------
// D[n][m] = sum_k Bt[n][k]*At[m][k]  (+ epilogue). At: MxK, Bt: NxK, row-major.
// epi==1: outT[n*M+m] = bf16(acc + bias[m])
// epi==2: t=n>>9, vox=n&511; out[(t*768+m)*512+vox] = x[...] + gamma[m]*(acc + bout[m])
__global__ __launch_bounds__(256) void k_gemm(const u16* __restrict__ At, const u16* __restrict__ Bt,
    const int M, const int K, const int mtiles, const int epi,
    const float* __restrict__ bias, u16* __restrict__ outT,
    const float* __restrict__ xres, const float* __restrict__ gamma,
    const float* __restrict__ bout, float* __restrict__ outp)
{
  __shared__ u16 lta[128*32];
  __shared__ u16 ltb[128*32];
  const int tid = threadIdx.x;
  const int l = tid & 63;
  const int wid = tid >> 6;
  const int wm = wid & 1, wn = wid >> 1;
  const int mt = blockIdx.x % mtiles, nt = blockIdx.x / mtiles;
  const f32x4 z = {0.f, 0.f, 0.f, 0.f};
  f32x4 acc[4][4];
  #pragma unroll
  for (int i = 0; i < 4; ++i)
    #pragma unroll
    for (int j = 0; j < 4; ++j) acc[i][j] = z;
  const int nk = K >> 5;
  const int sr = tid >> 2, sq = tid & 3;          // staging row / col-chunk
  const u16* gA = At + (size_t)(mt*128 + sr)*K + sq*8;
  const u16* gB = Bt + (size_t)(nt*128 + sr)*K + sq*8;
  u16* lA0 = lta + wid*512;                       // LDS elem offset = tid*8
  u16* lA1 = lta + 2048 + wid*512;
  u16* lB0 = ltb + wid*512;
  u16* lB1 = ltb + 2048 + wid*512;
  for (int kt = 0; kt < nk; ++kt){
    __syncthreads();                              // prev-iter LDS readers done
    gll16(gA + kt*32,              lA0);
    gll16(gA + kt*32 + (size_t)64*K, lA1);
    gll16(gB + kt*32,              lB0);
    gll16(gB + kt*32 + (size_t)64*K, lB1);
    __syncthreads();                              // compiler drains vmcnt here
    s16x8 fa[4], fb[4];
    #pragma unroll
    for (int f = 0; f < 4; ++f){
      fa[f] = *(const s16x8*)&ltb[(wn*64 + f*16 + (l&15))*32 + ((l>>4)<<3)];
      fb[f] = *(const s16x8*)&lta[(wm*64 + f*16 + (l&15))*32 + ((l>>4)<<3)];
    }
    #pragma unroll
    for (int fn = 0; fn < 4; ++fn)
      #pragma unroll
      for (int fm = 0; fm < 4; ++fm)
        acc[fn][fm] = __builtin_amdgcn_mfma_f32_16x16x32_bf16(fa[fn], fb[fm], acc[fn][fm], 0, 0, 0);
  }
  const int rsub = (l>>4) << 2, cbase = l & 15;
  if (epi == 1){
    #pragma unroll
    for (int fn = 0; fn < 4; ++fn)
      #pragma unroll
      for (int fm = 0; fm < 4; ++fm){
        const int n0 = nt*128 + wn*64 + fn*16 + rsub;
        const int m  = mt*128 + wm*64 + fm*16 + cbase;
        const float bm = bias[m];
        #pragma unroll
        for (int r = 0; r < 4; ++r)
          outT[(size_t)(n0 + r)*M + m] = f2bf(acc[fn][fm][r] + bm);
      }
  } else {
    #pragma unroll
    for (int fn = 0; fn < 4; ++fn)
      #pragma unroll
      for (int fm = 0; fm < 4; ++fm){
        const int n0 = nt*128 + wn*64 + fn*16 + rsub;
        const int m  = mt*128 + wm*64 + fm*16 + cbase;
        const int t = n0 >> 9, vox = n0 & 511;
        const size_t idx = ((size_t)t*768 + m)*512 + vox;
        const float gm = gamma[m], bo = bout[m];
        const float4 xv = *(const float4*)(xres + idx);
        float4 ov;
        ov.x = xv.x + gm*(acc[fn][fm][0] + bo);
        ov.y = xv.y + gm*(acc[fn][fm][1] + bo);
        ov.z = xv.z + gm*(acc[fn][fm][2] + bo);
        ov.w = xv.w + gm*(acc[fn][fm][3] + bo);
        *(float4*)(outp + idx) = ov;
      }
  }
}

// ---------------- K4: attention, 4 waves per (vox, head), 1 t-strip/wave ----
__device__ __forceinline__ void ln8(uint4 v, const float* wv, const float* bv, u16* dst){
  float e[8];
  const u32* p = (const u32*)&v;
  #pragma unroll
  for (int j = 0; j < 4; ++j){ e[2*j] = bfl(p[j]); e[2*j+1] = bfh(p[j]); }
  float s = 0.f, s2 = 0.f;
  #pragma unroll
  for (int j = 0; j < 8; ++j){ s += e[j]; s2 += e[j]*e[j]; }
  #pragma unroll
  for (int off = 1; off < 8; off <<= 1){ s += __shfl_xor(s, off); s2 += __shfl_xor(s2, off); }
  float mu  = s * (1.f/64.f);
  float inv = rsqrtf(s2*(1.f/64.f) - mu*mu + 1e-5f);
  u32 ow[4];
  #pragma unroll
  for (int j = 0; j < 4; ++j)
    ow[j] = pk2((e[2*j]-mu)*inv*wv[2*j] + bv[2*j],
                (e[2*j+1]-mu)*inv*wv[2*j+1] + bv[2*j+1]);
  uint4 q4; q4.x = ow[0]; q4.y = ow[1]; q4.z = ow[2]; q4.w = ow[3];
  *(uint4*)dst = q4;
}

__global__ __launch_bounds__(256) void k_attn(const u16* __restrict__ qkvT, const float* __restrict__ bias_d,
    const float* __restrict__ qn_w, const float* __restrict__ qn_b,
    const float* __restrict__ kn_w, const float* __restrict__ kn_b,
    u16* __restrict__ oT)
{
  __shared__ u16 qt[64][72], ktl[64][72], vtl[64][72];
  __shared__ float bd[128];
  const int tid = threadIdx.x;
  const int w = tid >> 6, l = tid & 63;
  const int he = blockIdx.x % 12;
  const int vox = blockIdx.x / 12;
  if (tid < 127) bd[tid] = bias_d[he*128 + tid];
  const int c0 = (l & 7) * 8;      // 8-elem channel chunk
  const int rl = l >> 3;           // row-in-group
  float qwv[8], qbv[8], kwv[8], kbv[8];
  *(float4*)&qwv[0] = *(const float4*)(qn_w + c0); *(float4*)&qwv[4] = *(const float4*)(qn_w + c0 + 4);
  *(float4*)&qbv[0] = *(const float4*)(qn_b + c0); *(float4*)&qbv[4] = *(const float4*)(qn_b + c0 + 4);
  *(float4*)&kwv[0] = *(const float4*)(kn_w + c0); *(float4*)&kwv[4] = *(const float4*)(kn_w + c0 + 4);
  *(float4*)&kbv[0] = *(const float4*)(kn_b + c0); *(float4*)&kbv[4] = *(const float4*)(kn_b + c0 + 4);
  #pragma unroll
  for (int i = 0; i < 2; ++i){
    const int r = w*16 + i*8 + rl;
    const u16* gb = qkvT + ((size_t)(r*512 + vox))*2304 + he*192 + c0;
    uint4 qv = *(const uint4*)(gb);
    uint4 kv = *(const uint4*)(gb + 64);
    uint4 vv = *(const uint4*)(gb + 128);
    ln8(qv, qwv, qbv, &qt[r][c0]);
    ln8(kv, kwv, kbv, &ktl[r][c0]);
    const u32* p = (const u32*)&vv;
    #pragma unroll
    for (int j = 0; j < 4; ++j){
      vtl[c0 + 2*j][r]     = (u16)(p[j] & 0xffffu);
      vtl[c0 + 2*j + 1][r] = (u16)(p[j] >> 16);
    }
  }
  __syncthreads();
  const int lc = l & 15, lh = l >> 4;
  const f32x4 z = {0.f, 0.f, 0.f, 0.f};
  f32x4 sa[4] = {z, z, z, z};
  #pragma unroll
  for (int ks = 0; ks < 2; ++ks){
    s16x8 fq = *(const s16x8*)&qt[w*16 + lc][ks*32 + lh*8];
    #pragma unroll
    for (int fc = 0; fc < 4; ++fc){
      s16x8 fk = *(const s16x8*)&ktl[fc*16 + lc][ks*32 + lh*8];
      sa[fc] = __builtin_amdgcn_mfma_f32_16x16x32_bf16(fq, fk, sa[fc], 0, 0, 0);
    }
  }
  u16 (*pt)[72] = qt;              // q strip dead after QK; reuse for P
  const int rsub = lh << 2;
  #pragma unroll
  for (int r = 0; r < 4; ++r){
    const int row = w*16 + rsub + r;
    float v0 = sa[0][r]*0.125f + bd[row - lc      + 63];
    float v1 = sa[1][r]*0.125f + bd[row - lc - 16 + 63];
    float v2 = sa[2][r]*0.125f + bd[row - lc - 32 + 63];
    float v3 = sa[3][r]*0.125f + bd[row - lc - 48 + 63];
    float m = fmaxf(fmaxf(v0, v1), fmaxf(v2, v3));
    #pragma unroll
    for (int off = 1; off < 16; off <<= 1) m = fmaxf(m, __shfl_xor(m, off));
    v0 = __expf(v0 - m); v1 = __expf(v1 - m); v2 = __expf(v2 - m); v3 = __expf(v3 - m);
    float sum = v0 + v1 + v2 + v3;
    #pragma unroll
    for (int off = 1; off < 16; off <<= 1) sum += __shfl_xor(sum, off);
    float rs = 1.0f / sum;
    pt[row][lc]      = f2bf(v0*rs);
    pt[row][lc + 16] = f2bf(v1*rs);
    pt[row][lc + 32] = f2bf(v2*rs);
    pt[row][lc + 48] = f2bf(v3*rs);
  }
  // own-wave P writes must complete before own-wave fragment reads (rule #18)
  asm volatile("s_waitcnt lgkmcnt(0)" ::: "memory");
  __builtin_amdgcn_sched_barrier(0);
  f32x4 oa[4] = {z, z, z, z};
  #pragma unroll
  for (int ks = 0; ks < 2; ++ks){
    s16x8 fp = *(const s16x8*)&pt[w*16 + lc][ks*32 + lh*8];
    #pragma unroll
    for (int fc = 0; fc < 4; ++fc){
      s16x8 fv = *(const s16x8*)&vtl[fc*16 + lc][ks*32 + lh*8];
      oa[fc] = __builtin_amdgcn_mfma_f32_16x16x32_bf16(fp, fv, oa[fc], 0, 0, 0);
    }
  }
  #pragma unroll
  for (int fc = 0; fc < 4; ++fc){
    const int c = fc*16 + lc;
    #pragma unroll
    for (int r = 0; r < 4; ++r){
      const int t = w*16 + rsub + r;
      oT[((size_t)(t*512 + vox))*768 + he*64 + c] = f2bf(oa[fc][r]);
    }
  }
}

// ---------------- launch ---------------------------------------------------
extern "C" void kernel_launch(void* const* d_in, const int* in_sizes, int n_in,
                              void* d_out, int out_size, void* d_ws, size_t ws_size,
                              hipStream_t stream) {
  (void)in_sizes; (void)n_in; (void)out_size; (void)ws_size;
  const float* x      = (const float*)d_in[0];
  const float* norm1w = (const float*)d_in[1];
  const float* w_in   = (const float*)d_in[2];
  const float* b_in   = (const float*)d_in[3];
  const float* qn_w   = (const float*)d_in[4];
  const float* qn_b   = (const float*)d_in[5];
  const float* kn_w   = (const float*)d_in[6];
  const float* kn_b   = (const float*)d_in[7];
  const float* rel    = (const float*)d_in[8];
  const float* w_out  = (const float*)d_in[9];
  const float* b_out  = (const float*)d_in[10];
  const float* gamma  = (const float*)d_in[11];
  float* out = (float*)d_out;

  char* ws = (char*)d_ws;
  float* stats  = (float*)(ws + 0);
  float* bias_d = (float*)(ws + 6144);
  u16*   winb   = (u16*)(ws + 12288);
  u16*   woutb  = (u16*)(ws + 3551232);
  u16*   xnT    = (u16*)(ws + 4730880);
  u16*   oT     = xnT;  // xnT dead after GEMM1; reuse for attention output
  u16*   qkvT   = (u16*)(ws + 55062528);

  k_bias <<<1,    128, 0, stream>>>(rel, bias_d);
  k_cast <<<2048, 256, 0, stream>>>(w_in, w_out, winb, woutb);
  k_stats<<<768,  256, 0, stream>>>(x, stats);
  k_norm <<<6144, 256, 0, stream>>>(x, stats, norm1w, xnT);
  k_gemm <<<4608, 256, 0, stream>>>(winb, xnT, 2304, 768, 18, 1,
                                    b_in, qkvT, nullptr, nullptr, nullptr, nullptr);
  k_attn <<<6144, 256, 0, stream>>>(qkvT, bias_d, qn_w, qn_b, kn_w, kn_b, oT);
  k_gemm <<<1536, 256, 0, stream>>>(woutb, oT, 768, 768, 6, 2,
                                    nullptr, nullptr, x, gamma, b_out, out);
}

// Round 3
// 538.324 us; speedup vs baseline: 1.1232x; 1.0663x over previous
//
#include <hip/hip_runtime.h>

// AttentionBlock: GN -> 1x1x1 conv (QKV) -> per-(voxel,head) attention with
// T5 rel-pos bias + q/k LayerNorm -> out-proj -> x + gamma*o.
// Shapes: T=64,B=1,C=768,H=W=D=8 (VOX=512), He=12, hd=64, groups=12.
//
// R3: k_gemm256 replaces k_gemm for both GEMMs: 256x256 tile, BK=32, 8 waves
// (2M x 4N), ring-2 LDS with EARLY stage / LATE vmcnt(0) drain, raw s_barrier
// (1 per K-tile), bank-balanced swizzled frag reads (lane-constant XOR,
// pre-swizzled global staging source), vectorized epilogues (operand order
// per-epilogue so the store-contiguous dim lands in the register index).

typedef unsigned int u32;
typedef unsigned short u16;
typedef __attribute__((ext_vector_type(4))) float f32x4;
typedef __attribute__((ext_vector_type(8))) short s16x8;

__device__ __forceinline__ float bfl(u32 w){ union{u32 i; float f;} u; u.i = w<<16; return u.f; }
__device__ __forceinline__ float bfh(u32 w){ union{u32 i; float f;} u; u.i = w & 0xffff0000u; return u.f; }
__device__ __forceinline__ u16 f2bf(float f){ union{float ff; u32 i;} u; u.ff = f; u32 r = u.i + 0x7fffu + ((u.i>>16)&1u); return (u16)(r>>16); }
__device__ __forceinline__ u32 pk2(float a, float b){ return (u32)f2bf(a) | ((u32)f2bf(b)<<16); }

__device__ __forceinline__ void gll16(const u16* g, u16* l){
  __builtin_amdgcn_global_load_lds((const __attribute__((address_space(1))) void*)g,
                                   (__attribute__((address_space(3))) void*)l, 16, 0, 0);
}

// ---------------- K0a: rel-pos bias table (bucket depends only on t-s) -----
__global__ void k_bias(const float* __restrict__ rel, float* __restrict__ bias_d){
  int d = threadIdx.x;
  if (d < 127){
    int delta = d - 63;                    // t - s
    int ret = (delta < 0) ? 16 : 0;
    int a = delta < 0 ? -delta : delta;
    int bkt;
    if (a < 8) bkt = a;
    else {
      float lr = (logf((float)a * 0.125f) / logf(16.0f)) * 8.0f;
      int vl = 8 + (int)lr;
      bkt = vl > 15 ? 15 : vl;
    }
    bkt += ret;
    for (int he = 0; he < 12; ++he) bias_d[he*128 + d] = rel[bkt*12 + he];
  }
}

// ---------------- K0b: cast weights to bf16 --------------------------------
__global__ void k_cast(const float* __restrict__ a, const float* __restrict__ b,
                       u16* __restrict__ ab, u16* __restrict__ bb){
  const int n1 = 2304*768, n2 = 768*768;
  for (int i = blockIdx.x*blockDim.x + threadIdx.x; i < n1+n2; i += gridDim.x*blockDim.x){
    if (i < n1) ab[i] = f2bf(a[i]);
    else        bb[i-n1] = f2bf(b[i-n1]);
  }
}

// ---------------- K1: GroupNorm stats (one block per (tb,g)) ---------------
__global__ __launch_bounds__(256) void k_stats(const float* __restrict__ x, float* __restrict__ stats){
  __shared__ float red[8];
  const float4* xb = (const float4*)(x + (size_t)blockIdx.x * 32768);
  float s = 0.f, s2 = 0.f;
  for (int i = threadIdx.x; i < 8192; i += 256){
    float4 v = xb[i];
    s  += v.x + v.y + v.z + v.w;
    s2 += v.x*v.x + v.y*v.y + v.z*v.z + v.w*v.w;
  }
  #pragma unroll
  for (int off = 32; off; off >>= 1){ s += __shfl_down(s, off); s2 += __shfl_down(s2, off); }
  int wid = threadIdx.x >> 6;
  if ((threadIdx.x & 63) == 0){ red[wid*2] = s; red[wid*2+1] = s2; }
  __syncthreads();
  if (threadIdx.x == 0){
    float ts = 0.f, ts2 = 0.f;
    for (int w = 0; w < 4; ++w){ ts += red[w*2]; ts2 += red[w*2+1]; }
    float mu  = ts * (1.f/32768.f);
    float var = ts2 * (1.f/32768.f) - mu*mu;
    stats[blockIdx.x*2]   = mu;
    stats[blockIdx.x*2+1] = rsqrtf(var + 1e-5f);
  }
}

// ---------------- K2: normalize + transpose -> xnT[n][c] bf16 --------------
__global__ __launch_bounds__(256) void k_norm(const float* __restrict__ x, const float* __restrict__ stats,
                                              const float* __restrict__ w1, u16* __restrict__ xnT){
  __shared__ float ld[64][65];
  const int b = blockIdx.x;
  const int tb = b / 96, rem = b % 96, cb = rem >> 3, vb = rem & 7;
  const float mu  = stats[(tb*12+cb)*2];
  const float inv = stats[(tb*12+cb)*2+1];
  const int tid = threadIdx.x;
  #pragma unroll
  for (int it = 0; it < 4; ++it){
    int chunk = it*256 + tid;
    int cl = chunk >> 4, v4 = chunk & 15;
    float w = w1[cb*64 + cl] * inv;
    float4 v = *(const float4*)(x + ((size_t)(tb*768 + cb*64 + cl)*512 + vb*64 + v4*4));
    ld[cl][v4*4+0] = (v.x - mu) * w;
    ld[cl][v4*4+1] = (v.y - mu) * w;
    ld[cl][v4*4+2] = (v.z - mu) * w;
    ld[cl][v4*4+3] = (v.w - mu) * w;
  }
  __syncthreads();
  #pragma unroll
  for (int it = 0; it < 2; ++it){
    int chunk = it*256 + tid;
    int vl = chunk >> 3, p = chunk & 7;
    u32 ow[4];
    #pragma unroll
    for (int j = 0; j < 4; ++j)
      ow[j] = pk2(ld[p*8 + j*2][vl], ld[p*8 + j*2 + 1][vl]);
    uint4 q4; q4.x = ow[0]; q4.y = ow[1]; q4.z = ow[2]; q4.w = ow[3];
    *(uint4*)(xnT + ((size_t)(tb*512 + vb*64 + vl)*768 + cb*64 + p*8)) = q4;
  }
}

// ---------------- K3/K5: 256x256-tile bf16 MFMA GEMM, ring-2 pipeline ------
// D[n][m] = sum_k Bt[n][k]*At[m][k]. At: MxK row-major, Bt: NxK row-major.
// K=768 fixed. 8 waves: wm=wid&1 (m-half, 128 rows), wn=wid>>1 (n-quarter, 64).
// EPI==1: outT[n*M + m] = bf16(acc + bias[m])        (m in reg idx -> 8B stores)
// EPI==2: out[(t*768+m)*512+vox] = x + gamma*(acc+bout) (n in reg idx -> float4)
template<int EPI>
__global__ __launch_bounds__(512, 2) void k_gemm256(
    const u16* __restrict__ At, const u16* __restrict__ Bt,
    const int M, const int mtiles,
    const float* __restrict__ bias, u16* __restrict__ outT,
    const float* __restrict__ xres, const float* __restrict__ gamma,
    const float* __restrict__ bout, float* __restrict__ outp)
{
  __shared__ u16 lds[2][2][8192];          // [slot][A|B][256 rows x 32 k]
  const int K = 768, nkt = 24;
  const int tid = threadIdx.x;
  const int l = tid & 63, wid = tid >> 6;
  const int wm = wid & 1, wn = wid >> 1;
  // XCD-aware swizzle (grid % 8 == 0 for both call sites)
  const int cpx = gridDim.x >> 3;
  const int wg = (blockIdx.x & 7) * cpx + (blockIdx.x >> 3);
  const int mt = wg % mtiles, nt = wg / mtiles;

  // staging: thread t loads row srow (and srow+128), 16B chunk cg (pre-swizzled)
  const int srow = tid >> 2;
  const int cg = (tid ^ (tid >> 3)) & 3;
  const u16* gA = At + (size_t)(mt*256 + srow)*K + cg*8;
  const u16* gB = Bt + (size_t)(nt*256 + srow)*K + cg*8;

  // frag-read offsets: row = base + (l&15), chunk = (l>>4) XOR-swizzled (lane-const)
  const int cSwz = ((l>>4) ^ (l>>1)) & 3;
  const int aoff = (wm*128 + (l&15))*32 + cSwz*8;   // + mf*512
  const int boff = (wn*64  + (l&15))*32 + cSwz*8;   // + nf*512

  f32x4 acc[8][4];
  const f32x4 z = {0.f, 0.f, 0.f, 0.f};
  #pragma unroll
  for (int i = 0; i < 8; ++i)
    #pragma unroll
    for (int j = 0; j < 4; ++j) acc[i][j] = z;

  #define STAGE(slot, kt) do { \
    u16* la = &lds[slot][0][0] + tid*8; \
    u16* lb = &lds[slot][1][0] + tid*8; \
    gll16(gA + (kt)*32,                 la); \
    gll16(gA + (kt)*32 + (size_t)128*K, la + 4096); \
    gll16(gB + (kt)*32,                 lb); \
    gll16(gB + (kt)*32 + (size_t)128*K, lb + 4096); \
  } while(0)

  STAGE(0, 0);
  asm volatile("s_waitcnt vmcnt(0)" ::: "memory");
  __builtin_amdgcn_s_barrier();
  __builtin_amdgcn_sched_barrier(0);

  for (int kt = 0; kt < nkt; ++kt){
    const int slot = kt & 1;
    if (kt + 1 < nkt) STAGE(slot ^ 1, kt + 1);   // early issue; drains late
    const u16* Ab = &lds[slot][0][0];
    const u16* Bb = &lds[slot][1][0];
    s16x8 fa[8], fb[4];
    #pragma unroll
    for (int mf = 0; mf < 8; ++mf) fa[mf] = *(const s16x8*)(Ab + aoff + mf*512);
    #pragma unroll
    for (int nf = 0; nf < 4; ++nf) fb[nf] = *(const s16x8*)(Bb + boff + nf*512);
    #pragma unroll
    for (int mf = 0; mf < 8; ++mf)
      #pragma unroll
      for (int nf = 0; nf < 4; ++nf){
        if (EPI == 1)  // rows=m (reg idx), cols=n (lane idx)
          acc[mf][nf] = __builtin_amdgcn_mfma_f32_16x16x32_bf16(fa[mf], fb[nf], acc[mf][nf], 0, 0, 0);
        else           // rows=n (reg idx), cols=m (lane idx)
          acc[mf][nf] = __builtin_amdgcn_mfma_f32_16x16x32_bf16(fb[nf], fa[mf], acc[mf][nf], 0, 0, 0);
      }
    if (kt + 1 < nkt){
      asm volatile("s_waitcnt vmcnt(0)" ::: "memory");  // next tile landed
      __builtin_amdgcn_s_barrier();                     // raw: no forced drain beyond ours
      __builtin_amdgcn_sched_barrier(0);                // pin stage issue below barrier
    }
  }
  #undef STAGE

  if (EPI == 1){
    const int nbase = nt*256 + wn*64 + (l & 15);
    const int mbase = mt*256 + wm*128 + ((l >> 4) << 2);
    #pragma unroll
    for (int mf = 0; mf < 8; ++mf){
      const int m0 = mbase + mf*16;
      const float4 b4 = *(const float4*)(bias + m0);
      #pragma unroll
      for (int nf = 0; nf < 4; ++nf){
        const int n = nbase + nf*16;
        uint2 u;
        u.x = pk2(acc[mf][nf][0] + b4.x, acc[mf][nf][1] + b4.y);
        u.y = pk2(acc[mf][nf][2] + b4.z, acc[mf][nf][3] + b4.w);
        *(uint2*)(outT + (size_t)n*M + m0) = u;
      }
    }
  } else {
    const int nbase = nt*256 + wn*64 + ((l >> 4) << 2);
    const int mbase = mt*256 + wm*128 + (l & 15);
    #pragma unroll
    for (int mf = 0; mf < 8; ++mf){
      const int m = mbase + mf*16;
      const float gm = gamma[m], bo = bout[m];
      #pragma unroll
      for (int nf = 0; nf < 4; ++nf){
        const int n0 = nbase + nf*16;
        const int t = n0 >> 9, vox = n0 & 511;
        const size_t idx = ((size_t)t*768 + m)*512 + vox;
        const float4 xv = *(const float4*)(xres + idx);
        float4 ov;
        ov.x = xv.x + gm*(acc[mf][nf][0] + bo);
        ov.y = xv.y + gm*(acc[mf][nf][1] + bo);
        ov.z = xv.z + gm*(acc[mf][nf][2] + bo);
        ov.w = xv.w + gm*(acc[mf][nf][3] + bo);
        *(float4*)(outp + idx) = ov;
      }
    }
  }
}

// ---------------- K4: attention, 4 waves per (vox, head), 1 t-strip/wave ----
__device__ __forceinline__ void ln8(uint4 v, const float* wv, const float* bv, u16* dst){
  float e[8];
  const u32* p = (const u32*)&v;
  #pragma unroll
  for (int j = 0; j < 4; ++j){ e[2*j] = bfl(p[j]); e[2*j+1] = bfh(p[j]); }
  float s = 0.f, s2 = 0.f;
  #pragma unroll
  for (int j = 0; j < 8; ++j){ s += e[j]; s2 += e[j]*e[j]; }
  #pragma unroll
  for (int off = 1; off < 8; off <<= 1){ s += __shfl_xor(s, off); s2 += __shfl_xor(s2, off); }
  float mu  = s * (1.f/64.f);
  float inv = rsqrtf(s2*(1.f/64.f) - mu*mu + 1e-5f);
  u32 ow[4];
  #pragma unroll
  for (int j = 0; j < 4; ++j)
    ow[j] = pk2((e[2*j]-mu)*inv*wv[2*j] + bv[2*j],
                (e[2*j+1]-mu)*inv*wv[2*j+1] + bv[2*j+1]);
  uint4 q4; q4.x = ow[0]; q4.y = ow[1]; q4.z = ow[2]; q4.w = ow[3];
  *(uint4*)dst = q4;
}

__global__ __launch_bounds__(256) void k_attn(const u16* __restrict__ qkvT, const float* __restrict__ bias_d,
    const float* __restrict__ qn_w, const float* __restrict__ qn_b,
    const float* __restrict__ kn_w, const float* __restrict__ kn_b,
    u16* __restrict__ oT)
{
  __shared__ u16 qt[64][72], ktl[64][72], vtl[64][72];
  __shared__ float bd[128];
  const int tid = threadIdx.x;
  const int w = tid >> 6, l = tid & 63;
  const int he = blockIdx.x % 12;
  const int vox = blockIdx.x / 12;
  if (tid < 127) bd[tid] = bias_d[he*128 + tid];
  const int c0 = (l & 7) * 8;      // 8-elem channel chunk
  const int rl = l >> 3;           // row-in-group
  float qwv[8], qbv[8], kwv[8], kbv[8];
  *(float4*)&qwv[0] = *(const float4*)(qn_w + c0); *(float4*)&qwv[4] = *(const float4*)(qn_w + c0 + 4);
  *(float4*)&qbv[0] = *(const float4*)(qn_b + c0); *(float4*)&qbv[4] = *(const float4*)(qn_b + c0 + 4);
  *(float4*)&kwv[0] = *(const float4*)(kn_w + c0); *(float4*)&kwv[4] = *(const float4*)(kn_w + c0 + 4);
  *(float4*)&kbv[0] = *(const float4*)(kn_b + c0); *(float4*)&kbv[4] = *(const float4*)(kn_b + c0 + 4);
  #pragma unroll
  for (int i = 0; i < 2; ++i){
    const int r = w*16 + i*8 + rl;
    const u16* gb = qkvT + ((size_t)(r*512 + vox))*2304 + he*192 + c0;
    uint4 qv = *(const uint4*)(gb);
    uint4 kv = *(const uint4*)(gb + 64);
    uint4 vv = *(const uint4*)(gb + 128);
    ln8(qv, qwv, qbv, &qt[r][c0]);
    ln8(kv, kwv, kbv, &ktl[r][c0]);
    const u32* p = (const u32*)&vv;
    #pragma unroll
    for (int j = 0; j < 4; ++j){
      vtl[c0 + 2*j][r]     = (u16)(p[j] & 0xffffu);
      vtl[c0 + 2*j + 1][r] = (u16)(p[j] >> 16);
    }
  }
  __syncthreads();
  const int lc = l & 15, lh = l >> 4;
  const f32x4 z = {0.f, 0.f, 0.f, 0.f};
  f32x4 sa[4] = {z, z, z, z};
  #pragma unroll
  for (int ks = 0; ks < 2; ++ks){
    s16x8 fq = *(const s16x8*)&qt[w*16 + lc][ks*32 + lh*8];
    #pragma unroll
    for (int fc = 0; fc < 4; ++fc){
      s16x8 fk = *(const s16x8*)&ktl[fc*16 + lc][ks*32 + lh*8];
      sa[fc] = __builtin_amdgcn_mfma_f32_16x16x32_bf16(fq, fk, sa[fc], 0, 0, 0);
    }
  }
  u16 (*pt)[72] = qt;              // q strip dead after QK; reuse for P
  const int rsub = lh << 2;
  #pragma unroll
  for (int r = 0; r < 4; ++r){
    const int row = w*16 + rsub + r;
    float v0 = sa[0][r]*0.125f + bd[row - lc      + 63];
    float v1 = sa[1][r]*0.125f + bd[row - lc - 16 + 63];
    float v2 = sa[2][r]*0.125f + bd[row - lc - 32 + 63];
    float v3 = sa[3][r]*0.125f + bd[row - lc - 48 + 63];
    float m = fmaxf(fmaxf(v0, v1), fmaxf(v2, v3));
    #pragma unroll
    for (int off = 1; off < 16; off <<= 1) m = fmaxf(m, __shfl_xor(m, off));
    v0 = __expf(v0 - m); v1 = __expf(v1 - m); v2 = __expf(v2 - m); v3 = __expf(v3 - m);
    float sum = v0 + v1 + v2 + v3;
    #pragma unroll
    for (int off = 1; off < 16; off <<= 1) sum += __shfl_xor(sum, off);
    float rs = 1.0f / sum;
    pt[row][lc]      = f2bf(v0*rs);
    pt[row][lc + 16] = f2bf(v1*rs);
    pt[row][lc + 32] = f2bf(v2*rs);
    pt[row][lc + 48] = f2bf(v3*rs);
  }
  // own-wave P writes must complete before own-wave fragment reads (rule #18)
  asm volatile("s_waitcnt lgkmcnt(0)" ::: "memory");
  __builtin_amdgcn_sched_barrier(0);
  f32x4 oa[4] = {z, z, z, z};
  #pragma unroll
  for (int ks = 0; ks < 2; ++ks){
    s16x8 fp = *(const s16x8*)&pt[w*16 + lc][ks*32 + lh*8];
    #pragma unroll
    for (int fc = 0; fc < 4; ++fc){
      s16x8 fv = *(const s16x8*)&vtl[fc*16 + lc][ks*32 + lh*8];
      oa[fc] = __builtin_amdgcn_mfma_f32_16x16x32_bf16(fp, fv, oa[fc], 0, 0, 0);
    }
  }
  #pragma unroll
  for (int fc = 0; fc < 4; ++fc){
    const int c = fc*16 + lc;
    #pragma unroll
    for (int r = 0; r < 4; ++r){
      const int t = w*16 + rsub + r;
      oT[((size_t)(t*512 + vox))*768 + he*64 + c] = f2bf(oa[fc][r]);
    }
  }
}

// ---------------- launch ---------------------------------------------------
extern "C" void kernel_launch(void* const* d_in, const int* in_sizes, int n_in,
                              void* d_out, int out_size, void* d_ws, size_t ws_size,
                              hipStream_t stream) {
  (void)in_sizes; (void)n_in; (void)out_size; (void)ws_size;
  const float* x      = (const float*)d_in[0];
  const float* norm1w = (const float*)d_in[1];
  const float* w_in   = (const float*)d_in[2];
  const float* b_in   = (const float*)d_in[3];
  const float* qn_w   = (const float*)d_in[4];
  const float* qn_b   = (const float*)d_in[5];
  const float* kn_w   = (const float*)d_in[6];
  const float* kn_b   = (const float*)d_in[7];
  const float* rel    = (const float*)d_in[8];
  const float* w_out  = (const float*)d_in[9];
  const float* b_out  = (const float*)d_in[10];
  const float* gamma  = (const float*)d_in[11];
  float* out = (float*)d_out;

  char* ws = (char*)d_ws;
  float* stats  = (float*)(ws + 0);
  float* bias_d = (float*)(ws + 6144);
  u16*   winb   = (u16*)(ws + 12288);
  u16*   woutb  = (u16*)(ws + 3551232);
  u16*   xnT    = (u16*)(ws + 4730880);
  u16*   oT     = xnT;  // xnT dead after GEMM1; reuse for attention output
  u16*   qkvT   = (u16*)(ws + 55062528);

  k_bias <<<1,    128, 0, stream>>>(rel, bias_d);
  k_cast <<<2048, 256, 0, stream>>>(w_in, w_out, winb, woutb);
  k_stats<<<768,  256, 0, stream>>>(x, stats);
  k_norm <<<6144, 256, 0, stream>>>(x, stats, norm1w, xnT);
  k_gemm256<1><<<1152, 512, 0, stream>>>(winb, xnT, 2304, 9,
                                         b_in, qkvT, nullptr, nullptr, nullptr, nullptr);
  k_attn <<<6144, 256, 0, stream>>>(qkvT, bias_d, qn_w, qn_b, kn_w, kn_b, oT);
  k_gemm256<2><<<384, 512, 0, stream>>>(woutb, oT, 768, 3,
                                        nullptr, nullptr, x, gamma, b_out, out);
}